// Round 4
// baseline (278.695 us; speedup 1.0000x reference)
//
#include <hip/hip_runtime.h>
#include <hip/hip_bf16.h>

#define N_NODES 131072
#define DIM 128
#define NG 512

typedef __bf16 bf16;
typedef __attribute__((ext_vector_type(8))) __bf16 bf16x8;
typedef __attribute__((ext_vector_type(4))) float f32x4;

// 1/sqrt(128) * log2(e) — folded into Wk/bk so attention scores exp2 directly
#define KSC 0.12753785006196978f

// workspace layout (bytes)
#define WS_STARTS 0                         // 513 ints
#define WS_WF     8192                      // fragment-ordered W: 3*8*4*64*8 bf16 = 98304 B
#define WS_KB     131072                    // N*128 bf16
#define WS_QB     (131072 + 33554432)
#define WS_VTB    (131072 + 2*33554432)     // Vt[d][n]: 128 x N bf16

__device__ __forceinline__ void gl_lds16(const void* g, void* l) {
    __builtin_amdgcn_global_load_lds(
        (const __attribute__((address_space(1))) unsigned int*)g,
        (__attribute__((address_space(3))) unsigned int*)l, 16, 0, 0);
}

__global__ void seg_starts_kernel(const int* __restrict__ batch, int* __restrict__ starts) {
    int g = threadIdx.x;                    // 0..511
    int lo = 0, hi = N_NODES;
    while (lo < hi) { int mid = (lo + hi) >> 1; if (batch[mid] < g) lo = mid + 1; else hi = mid; }
    starts[g] = lo;
    if (g == 0) starts[NG] = N_NODES;
}

// Emit W in B-fragment order: Wf[((mat*8+n0)*4+ks)*64 + lane] is the bf16x8 that
// lane reads for MFMA (col = n0*16 + (lane&15), k = ks*32 + (lane>>4)*8 + j).
// Wk (mat 0) is pre-scaled by KSC so attention scores are exp2-ready.
__global__ void wconv_kernel(const float* __restrict__ Wk, const float* __restrict__ Wq,
                             const float* __restrict__ Wv, bf16* __restrict__ Wf) {
    int f = blockIdx.x * 256 + threadIdx.x;  // 0..6143
    int lane = f & 63, ks = (f >> 6) & 3, n0 = (f >> 8) & 7, mat = f >> 11;
    const float* src = (mat == 0) ? Wk : ((mat == 1) ? Wq : Wv);
    float sc = (mat == 0) ? KSC : 1.0f;
    int col = n0 * 16 + (lane & 15);
    int koff = ks * 32 + (lane >> 4) * 8;
    const float* p = src + col * DIM + koff;
    bf16* dst = Wf + (size_t)f * 8;
    #pragma unroll
    for (int j = 0; j < 8; j++) dst[j] = (bf16)(p[j] * sc);
}

// QKV projection: out = x @ W^T + b, stored bf16 (x read ONCE per block, 3 mats).
// V stored transposed: Vt[d][n]. All global stores 16B coalesced via LDS tile.
__global__ __launch_bounds__(256) void qkv_kernel(
        const float* __restrict__ x, const bf16* __restrict__ Wf,
        const float* __restrict__ bk, const float* __restrict__ bq, const float* __restrict__ bv,
        bf16* __restrict__ Kb, bf16* __restrict__ Qb, bf16* __restrict__ Vtb) {
    __shared__ bf16 tile[128 * 136];         // 34816 B; x-tile first, then C-tile per mat
    const int tid = threadIdx.x;
    const int w = tid >> 6, lane = tid & 63, q = lane >> 4, i = lane & 15;
    const int r0 = blockIdx.x * 128;

    {   // stage x tile (coalesced fp32 loads -> bf16 LDS)
        #pragma unroll
        for (int it = 0; it < 16; it++) {
            int e = tid * 4 + it * 1024;     // element in 128x128 tile
            int row = e >> 7, col = e & 127;
            float4 u = *(const float4*)(x + (size_t)(r0 + row) * DIM + col);
            bf16 b[4] = {(bf16)u.x, (bf16)u.y, (bf16)u.z, (bf16)u.w};
            *(ushort4*)&tile[row * 136 + col] = *(ushort4*)b;
        }
    }
    __syncthreads();

    // A fragments from LDS: rows r0 + w*32 + rg*16 + i
    bf16x8 af[2][4];
    #pragma unroll
    for (int rg = 0; rg < 2; rg++)
        #pragma unroll
        for (int ks = 0; ks < 4; ks++)
            af[rg][ks] = *(const bf16x8*)&tile[(w * 32 + rg * 16 + i) * 136 + ks * 32 + q * 8];
    __syncthreads();                         // frag reads done before tile reuse

    for (int mat = 0; mat < 3; mat++) {
        const float* bias = (mat == 0) ? bk : ((mat == 1) ? bq : bv);
        const float bscale = (mat == 0) ? KSC : 1.0f;
        for (int n0 = 0; n0 < 8; n0++) {
            int col = n0 * 16 + i;
            float bias_v = bias[col] * bscale;
            f32x4 acc0 = {0,0,0,0}, acc1 = {0,0,0,0};
            #pragma unroll
            for (int ks = 0; ks < 4; ks++) {
                bf16x8 bw = *(const bf16x8*)(Wf + ((size_t)((mat * 8 + n0) * 4 + ks) * 64 + lane) * 8);
                acc0 = __builtin_amdgcn_mfma_f32_16x16x32_bf16(af[0][ks], bw, acc0, 0, 0, 0);
                acc1 = __builtin_amdgcn_mfma_f32_16x16x32_bf16(af[1][ks], bw, acc1, 0, 0, 0);
            }
            #pragma unroll
            for (int rg = 0; rg < 2; rg++) {
                f32x4 a = rg ? acc1 : acc0;
                #pragma unroll
                for (int r = 0; r < 4; r++) {
                    int rowl = w * 32 + rg * 16 + q * 4 + r;
                    bf16 hv = (bf16)(a[r] + bias_v);
                    if (mat < 2) tile[rowl * 136 + col] = hv;   // row-major [row][d]
                    else         tile[col * 136 + rowl] = hv;   // transposed [d][row]
                }
            }
        }
        __syncthreads();
        {   // coalesced 16B stores
            int row = tid >> 1, half = tid & 1;
            const uint4* src = (const uint4*)(tile + row * 136 + half * 64);
            uint4* dst;
            if (mat == 0)      dst = (uint4*)(Kb  + (size_t)(r0 + row) * DIM + half * 64);
            else if (mat == 1) dst = (uint4*)(Qb  + (size_t)(r0 + row) * DIM + half * 64);
            else               dst = (uint4*)(Vtb + (size_t)row * N_NODES + r0 + half * 64);
            #pragma unroll
            for (int j = 0; j < 8; j++) dst[j] = src[j];
        }
        __syncthreads();
    }
}

// Fused segment attention + residual + LayerNorm.
// R3 analysis: concurrency pinned at ~0.8 blocks/CU across 54/64/80KB LDS -> TLP is
// not coming. attn is HBM-LATENCY-bound: in-flight DMA (~6.7MB chip-wide at depth-1)
// == bandwidth-delay product -> 2.2 of 6.3 TB/s. Fix: depth-3 prefetch.
//  - 4-buffer LDS ring (128 KB, 1 block/CU by design), chunks mc..mc+2 in flight.
//  - counted vmcnt at the top barrier (T4): wait vmcnt(8) (= 2 chunks x 4 wave-DMAs
//    stay outstanding), NEVER vmcnt(0) in steady state. Raw s_barrier (no implicit
//    drain). Tail iterations step down 8 -> 4 -> 0.
//  - P overlays Qs[cur] after QK^T (mid raw barrier, lgkmcnt-only, as R3).
//  - grid dim3(NG,4): blocks of one graph land on the same XCD (id = g + 512*y,
//    same g => same id mod 8) for L2 reuse of shared Q/Vt chunks.
__global__ __launch_bounds__(512, 4) void attn_kernel(
        const float* __restrict__ x,
        const bf16* __restrict__ Kb, const bf16* __restrict__ Qb, const bf16* __restrict__ Vtb,
        const float* __restrict__ gamma, const float* __restrict__ beta,
        const int* __restrict__ starts, float* __restrict__ out) {
    __shared__ bf16 Qs[4][64 * 128];         // 4 x 16384 B ring; P overlays Qs[cur]
    __shared__ bf16 Vts[4][128 * 64];        // 4 x 16384 B ring   (total 131072 B)

    const int g = blockIdx.x;
    const int seg = starts[g];
    const int c = starts[g + 1] - seg;
    const int l0 = blockIdx.y * 128;
    if (l0 >= c) return;

    const int tid = threadIdx.x;
    const int w = tid >> 6, lane = tid & 63, q = lane >> 4, i = lane & 15;

    const int mstart = seg & ~7;             // 8-aligned -> 16B-aligned staging
    const int nch = (seg - mstart + c + 63) >> 6;   // >= 4 since c >= 192

    // async-stage one 64-m chunk: Q rows (64x128) + Vt rows (128x64), swizzled source.
    // 4 gl_lds16 per wave; LDS dest wave-uniform base + lane*16B (linear).
    auto stage = [&](int buf, int mb) {
        #pragma unroll
        for (int p = 0; p < 2; p++) {        // Q: 1 instr = 4 rows (16 lanes/row)
            int row = w * 8 + p * 4 + (lane >> 4);
            int gr = mb + row; if (gr > N_NODES - 1) gr = N_NODES - 1;
            gl_lds16(Qb + (size_t)gr * DIM + (((lane & 15) ^ (row & 7)) << 3),
                     &Qs[buf][(w * 8 + p * 4) * 128]);
        }
        #pragma unroll
        for (int p = 0; p < 2; p++) {        // Vt: 1 instr = 8 rows (8 lanes/row)
            int d = w * 16 + p * 8 + (lane >> 3);
            int mo = mb + (((lane & 7) ^ (d & 7)) << 3);
            if (mo > N_NODES - 8) mo = N_NODES - 8;
            gl_lds16(Vtb + (size_t)d * N_NODES + mo,
                     &Vts[buf][(w * 16 + p * 8) * 64]);
        }
    };

    // K fragments first (oldest vmem ops -> compiler's wait for them is precise)
    bf16x8 afK[4];
    {
        int lrow = l0 + w * 16 + i;
        if (lrow > c - 1) lrow = c - 1;
        const bf16* krow = Kb + (size_t)(seg + lrow) * DIM;
        #pragma unroll
        for (int ks = 0; ks < 4; ks++)
            afK[ks] = *(const bf16x8*)(krow + ks * 32 + q * 8);
    }

    stage(0, mstart);                        // fill the pipeline: 3 chunks in flight
    stage(1, mstart + 64);
    stage(2, mstart + 128);

    float li[4] = {0.0f, 0.0f, 0.0f, 0.0f};
    f32x4 Oc[8];
    #pragma unroll
    for (int t = 0; t < 8; t++) Oc[t] = (f32x4){0,0,0,0};

    const int f7 = i & 7;                    // LDS row&7 for all fragment rows (=i&7)
    const int mh = (i >> 3);

    for (int mc = 0; mc < nch; mc++) {
        const int cur = mc & 3;
        const int mbase = mstart + (mc << 6);
        const int ahead = nch - 1 - mc;      // chunks staged beyond mc (block-uniform)
        // counted wait: retire chunk mc's 4 DMAs, keep later chunks in flight
        if (ahead >= 2)      asm volatile("s_waitcnt vmcnt(8)" ::: "memory");
        else if (ahead == 1) asm volatile("s_waitcnt vmcnt(4)" ::: "memory");
        else                 asm volatile("s_waitcnt vmcnt(0)" ::: "memory");
        __builtin_amdgcn_s_barrier();
        __builtin_amdgcn_sched_barrier(0);
        if (mc + 3 < nch) stage((mc + 3) & 3, mbase + 192);  // overwrites buf (mc-1)&3

        const bf16* QsB = Qs[cur];
        const bf16* VtB = Vts[cur];
        bf16* Pw = &Qs[cur][w * 1024];       // wave-private 16x64 P slice (overlay)

        // S = K * Q^T (16 l-rows x 64 m-cols per wave), pre-scaled for exp2
        f32x4 s[4];
        __builtin_amdgcn_s_setprio(1);
        #pragma unroll
        for (int ti = 0; ti < 4; ti++) {
            f32x4 acc = {0,0,0,0};
            #pragma unroll
            for (int ks = 0; ks < 4; ks++) {
                bf16x8 bq = *(const bf16x8*)&QsB[(ti * 16 + i) * 128 + (((ks * 4 + q) ^ f7) << 3)];
                acc = __builtin_amdgcn_mfma_f32_16x16x32_bf16(afK[ks], bq, acc, 0, 0, 0);
            }
            s[ti] = acc;
        }
        __builtin_amdgcn_s_setprio(0);
        if (mc == 0 || mc == nch - 1) {      // only edge chunks can have invalid m
            #pragma unroll
            for (int ti = 0; ti < 4; ti++) {
                int mg = mbase + ti * 16 + i;
                bool valid = (mg >= seg) && (mg < seg + c);
                if (!valid) s[ti] = (f32x4){-1.0e30f, -1.0e30f, -1.0e30f, -1.0e30f};
            }
        }
        // p = exp2(s) in registers (overlaps barrier wait); accumulate l per-lane
        #pragma unroll
        for (int ti = 0; ti < 4; ti++)
            #pragma unroll
            for (int r = 0; r < 4; r++) {
                float pv = exp2f(s[ti][r]);
                li[r] += pv;
                s[ti][r] = pv;
            }

        // raw barrier: all waves' Qs[cur] reads retired; DMA (vmcnt) stays in flight
        asm volatile("s_waitcnt lgkmcnt(0)" ::: "memory");
        __builtin_amdgcn_s_barrier();
        __builtin_amdgcn_sched_barrier(0);

        // write P into overlay (C-layout -> A-layout, swizzled)
        #pragma unroll
        for (int ti = 0; ti < 4; ti++) {
            int mhi = 2 * ti + mh;           // m>>3
            #pragma unroll
            for (int r = 0; r < 4; r++) {
                int lr = q * 4 + r;
                Pw[lr * 64 + ((mhi ^ (lr & 7)) << 3) + f7] = (bf16)s[ti][r];
            }
        }

        // read P as A-fragments (same-wave LDS FIFO: no barrier needed)
        bf16x8 afP[2];
        #pragma unroll
        for (int k2 = 0; k2 < 2; k2++)
            afP[k2] = *(const bf16x8*)&Pw[i * 64 + (((k2 * 4 + q) ^ f7) << 3)];

        __builtin_amdgcn_s_setprio(1);
        #pragma unroll
        for (int dt = 0; dt < 8; dt++) {
            #pragma unroll
            for (int k2 = 0; k2 < 2; k2++) {
                bf16x8 bv = *(const bf16x8*)&VtB[(dt * 16 + i) * 64 + (((k2 * 4 + q) ^ f7) << 3)];
                Oc[dt] = __builtin_amdgcn_mfma_f32_16x16x32_bf16(afP[k2], bv, Oc[dt], 0, 0, 0);
            }
        }
        __builtin_amdgcn_s_setprio(0);
    }

    // one-time l reduction across the 16 i-lanes
    #pragma unroll
    for (int st = 1; st < 16; st <<= 1)
        #pragma unroll
        for (int r = 0; r < 4; r++)
            li[r] += __shfl_xor(li[r], st);

    // epilogue: z = O/l, h = x + z, LayerNorm, store fp32
    float gv[8], bvv[8];
    #pragma unroll
    for (int t = 0; t < 8; t++) { gv[t] = gamma[t * 16 + i]; bvv[t] = beta[t * 16 + i]; }
    for (int r = 0; r < 4; r++) {
        int lg = l0 + w * 16 + q * 4 + r;
        if (lg >= c) continue;               // uniform across the 16-lane shuffle group
        size_t node = (size_t)(seg + lg);
        float inv = 1.0f / li[r];
        const float* xr = x + node * DIM;
        float h[8], sum = 0.0f, ss = 0.0f;
        #pragma unroll
        for (int t = 0; t < 8; t++) {
            float hv = xr[t * 16 + i] + Oc[t][r] * inv;
            h[t] = hv;
            sum += hv; ss += hv * hv;
        }
        #pragma unroll
        for (int st = 1; st < 16; st <<= 1) {
            sum += __shfl_xor(sum, st);
            ss  += __shfl_xor(ss, st);
        }
        float mu = sum * (1.0f / 128.0f);
        float var = ss * (1.0f / 128.0f) - mu * mu;
        float rstd = rsqrtf(var + 1e-5f);
        float* op = out + node * DIM;
        #pragma unroll
        for (int t = 0; t < 8; t++)
            op[t * 16 + i] = (h[t] - mu) * rstd * gv[t] + bvv[t];
    }
}

extern "C" void kernel_launch(void* const* d_in, const int* in_sizes, int n_in,
                              void* d_out, int out_size, void* d_ws, size_t ws_size,
                              hipStream_t stream) {
    (void)in_sizes; (void)n_in; (void)out_size; (void)ws_size;
    const float* x     = (const float*)d_in[0];
    const float* Wk    = (const float*)d_in[1];
    const float* bk    = (const float*)d_in[2];
    const float* Wq    = (const float*)d_in[3];
    const float* bq    = (const float*)d_in[4];
    const float* Wv    = (const float*)d_in[5];
    const float* bv    = (const float*)d_in[6];
    const float* gamma = (const float*)d_in[7];
    const float* beta  = (const float*)d_in[8];
    const int*   batch = (const int*)d_in[9];
    float* out = (float*)d_out;

    char* ws = (char*)d_ws;
    int*  starts = (int*)(ws + WS_STARTS);
    bf16* Wf  = (bf16*)(ws + WS_WF);
    bf16* Kb  = (bf16*)(ws + WS_KB);
    bf16* Qb  = (bf16*)(ws + WS_QB);
    bf16* Vtb = (bf16*)(ws + WS_VTB);

    seg_starts_kernel<<<1, 512, 0, stream>>>(batch, starts);
    wconv_kernel<<<24, 256, 0, stream>>>(Wk, Wq, Wv, Wf);
    qkv_kernel<<<1024, 256, 0, stream>>>(x, Wf, bk, bq, bv, Kb, Qb, Vtb);
    attn_kernel<<<dim3(NG, 4), 512, 0, stream>>>(x, Kb, Qb, Vtb, gamma, beta, starts, out);
}

// Round 5
// 250.999 us; speedup vs baseline: 1.1103x; 1.1103x over previous
//
#include <hip/hip_runtime.h>
#include <hip/hip_bf16.h>

#define N_NODES 131072
#define DIM 128
#define NG 512

typedef __bf16 bf16;
typedef __attribute__((ext_vector_type(8))) __bf16 bf16x8;
typedef __attribute__((ext_vector_type(4))) float f32x4;

// 1/sqrt(128) * log2(e) — folded into Wk/bk so attention scores exp2 directly
#define KSC 0.12753785006196978f

// workspace layout (bytes)
#define WS_STARTS 0                         // 513 ints
#define WS_WF     8192                      // fragment-ordered W: 3*8*4*64*8 bf16 = 98304 B
#define WS_KB     131072                    // N*128 bf16
#define WS_QB     (131072 + 33554432)
#define WS_VTB    (131072 + 2*33554432)     // Vt[d][n]: 128 x N bf16

__device__ __forceinline__ void gl_lds16(const void* g, void* l) {
    __builtin_amdgcn_global_load_lds(
        (const __attribute__((address_space(1))) unsigned int*)g,
        (__attribute__((address_space(3))) unsigned int*)l, 16, 0, 0);
}

__global__ void seg_starts_kernel(const int* __restrict__ batch, int* __restrict__ starts) {
    int g = threadIdx.x;                    // 0..511
    int lo = 0, hi = N_NODES;
    while (lo < hi) { int mid = (lo + hi) >> 1; if (batch[mid] < g) lo = mid + 1; else hi = mid; }
    starts[g] = lo;
    if (g == 0) starts[NG] = N_NODES;
}

// Emit W in B-fragment order: Wf[((mat*8+n0)*4+ks)*64 + lane] is the bf16x8 that
// lane reads for MFMA (col = n0*16 + (lane&15), k = ks*32 + (lane>>4)*8 + j).
// Wk (mat 0) is pre-scaled by KSC so attention scores are exp2-ready.
__global__ void wconv_kernel(const float* __restrict__ Wk, const float* __restrict__ Wq,
                             const float* __restrict__ Wv, bf16* __restrict__ Wf) {
    int f = blockIdx.x * 256 + threadIdx.x;  // 0..6143
    int lane = f & 63, ks = (f >> 6) & 3, n0 = (f >> 8) & 7, mat = f >> 11;
    const float* src = (mat == 0) ? Wk : ((mat == 1) ? Wq : Wv);
    float sc = (mat == 0) ? KSC : 1.0f;
    int col = n0 * 16 + (lane & 15);
    int koff = ks * 32 + (lane >> 4) * 8;
    const float* p = src + col * DIM + koff;
    bf16* dst = Wf + (size_t)f * 8;
    #pragma unroll
    for (int j = 0; j < 8; j++) dst[j] = (bf16)(p[j] * sc);
}

// QKV projection: out = x @ W^T + b, stored bf16 (x read ONCE per block, 3 mats).
// V stored transposed: Vt[d][n]. All global stores 16B coalesced via LDS tile.
__global__ __launch_bounds__(256) void qkv_kernel(
        const float* __restrict__ x, const bf16* __restrict__ Wf,
        const float* __restrict__ bk, const float* __restrict__ bq, const float* __restrict__ bv,
        bf16* __restrict__ Kb, bf16* __restrict__ Qb, bf16* __restrict__ Vtb) {
    __shared__ bf16 tile[128 * 136];         // 34816 B; x-tile first, then C-tile per mat
    const int tid = threadIdx.x;
    const int w = tid >> 6, lane = tid & 63, q = lane >> 4, i = lane & 15;
    const int r0 = blockIdx.x * 128;

    {   // stage x tile (coalesced fp32 loads -> bf16 LDS)
        #pragma unroll
        for (int it = 0; it < 16; it++) {
            int e = tid * 4 + it * 1024;     // element in 128x128 tile
            int row = e >> 7, col = e & 127;
            float4 u = *(const float4*)(x + (size_t)(r0 + row) * DIM + col);
            bf16 b[4] = {(bf16)u.x, (bf16)u.y, (bf16)u.z, (bf16)u.w};
            *(ushort4*)&tile[row * 136 + col] = *(ushort4*)b;
        }
    }
    __syncthreads();

    // A fragments from LDS: rows r0 + w*32 + rg*16 + i
    bf16x8 af[2][4];
    #pragma unroll
    for (int rg = 0; rg < 2; rg++)
        #pragma unroll
        for (int ks = 0; ks < 4; ks++)
            af[rg][ks] = *(const bf16x8*)&tile[(w * 32 + rg * 16 + i) * 136 + ks * 32 + q * 8];
    __syncthreads();                         // frag reads done before tile reuse

    for (int mat = 0; mat < 3; mat++) {
        const float* bias = (mat == 0) ? bk : ((mat == 1) ? bq : bv);
        const float bscale = (mat == 0) ? KSC : 1.0f;
        for (int n0 = 0; n0 < 8; n0++) {
            int col = n0 * 16 + i;
            float bias_v = bias[col] * bscale;
            f32x4 acc0 = {0,0,0,0}, acc1 = {0,0,0,0};
            #pragma unroll
            for (int ks = 0; ks < 4; ks++) {
                bf16x8 bw = *(const bf16x8*)(Wf + ((size_t)((mat * 8 + n0) * 4 + ks) * 64 + lane) * 8);
                acc0 = __builtin_amdgcn_mfma_f32_16x16x32_bf16(af[0][ks], bw, acc0, 0, 0, 0);
                acc1 = __builtin_amdgcn_mfma_f32_16x16x32_bf16(af[1][ks], bw, acc1, 0, 0, 0);
            }
            #pragma unroll
            for (int rg = 0; rg < 2; rg++) {
                f32x4 a = rg ? acc1 : acc0;
                #pragma unroll
                for (int r = 0; r < 4; r++) {
                    int rowl = w * 32 + rg * 16 + q * 4 + r;
                    bf16 hv = (bf16)(a[r] + bias_v);
                    if (mat < 2) tile[rowl * 136 + col] = hv;   // row-major [row][d]
                    else         tile[col * 136 + rowl] = hv;   // transposed [d][row]
                }
            }
        }
        __syncthreads();
        {   // coalesced 16B stores
            int row = tid >> 1, half = tid & 1;
            const uint4* src = (const uint4*)(tile + row * 136 + half * 64);
            uint4* dst;
            if (mat == 0)      dst = (uint4*)(Kb  + (size_t)(r0 + row) * DIM + half * 64);
            else if (mat == 1) dst = (uint4*)(Qb  + (size_t)(r0 + row) * DIM + half * 64);
            else               dst = (uint4*)(Vtb + (size_t)row * N_NODES + r0 + half * 64);
            #pragma unroll
            for (int j = 0; j < 8; j++) dst[j] = src[j];
        }
        __syncthreads();
    }
}

// Fused segment attention + residual + LayerNorm.
// R5 theory: MfmaUtil pinned at 8-9% across ALL prior variants == the LDS-port-fed
// ceiling of "1 ds_read_b128 per MFMA" with ~1 block/CU. Fix BOTH terms:
//  - 2 MFMAs per LDS B-read (32 l-rows/wave, shared bq/bv) -> port ceiling x2.
//  - 48 KB LDS (3-buffer ring of 32-m chunks) -> 3 blocks/CU = 12 waves, so
//    independent blocks fill each other's barrier/DMA stall phases.
//  - counted vmcnt(4) at the top barrier (depth-2 prefetch in flight), raw
//    s_barrier, P overlays Qs[cur] after a lgkmcnt-only mid barrier.
//  - all three LDS streams (Q, Vt, P) XOR-swizzled 2-way-clean; DMA swizzle is
//    applied on the global source (linear LDS dest), VALU-written P swizzles
//    both sides in-kernel. tvi = (i ^ (i>>2)) & 3 is the shared read-side term.
__global__ __launch_bounds__(256, 3) void attn_kernel(
        const float* __restrict__ x,
        const bf16* __restrict__ Kb, const bf16* __restrict__ Qb, const bf16* __restrict__ Vtb,
        const float* __restrict__ gamma, const float* __restrict__ beta,
        const int* __restrict__ starts, float* __restrict__ out) {
    __shared__ bf16 Qs[3][32 * 128];         // 3 x 8192 B; P overlays Qs[cur]
    __shared__ bf16 Vts[3][128 * 32];        // 3 x 8192 B   (total 49152 B -> 3 blocks/CU)

    const int g = blockIdx.x;
    const int seg = starts[g];
    const int c = starts[g + 1] - seg;
    const int l0 = blockIdx.y * 128;
    if (l0 >= c) return;

    const int tid = threadIdx.x;
    const int w = tid >> 6, lane = tid & 63, q = lane >> 4, i = lane & 15;

    const int mstart = seg & ~7;             // 8-aligned -> 16B-aligned staging
    const int nch = (seg - mstart + c + 31) >> 5;   // 32-m chunks (>= 6 since c >= 192)

    // async-stage one 32-m chunk: Q rows (32x128) + Vt rows (128x32), swizzled source.
    // 4 gl_lds16 per wave (2 Q + 2 Vt); LDS dest wave-uniform base + lane*16B (linear).
    auto stage = [&](int buf, int mb) {
        #pragma unroll
        for (int p = 0; p < 2; p++) {        // Q: 1 instr = 4 rows (16 lanes/row)
            int row = w * 8 + p * 4 + (lane >> 4);
            int gr = mb + row; if (gr > N_NODES - 1) gr = N_NODES - 1;
            gl_lds16(Qb + (size_t)gr * DIM + (((lane & 15) ^ (row & 7)) << 3),
                     &Qs[buf][(w * 8 + p * 4) * 128]);
        }
        #pragma unroll
        for (int p = 0; p < 2; p++) {        // Vt: 1 instr = 16 rows (4 lanes/row)
            int d = w * 32 + p * 16 + (lane >> 2);
            int tvd = ((lane >> 2) ^ (lane >> 4)) & 3;       // = (d ^ (d>>2)) & 3
            int mo = mb + (((lane & 3) ^ tvd) << 3);
            if (mo > N_NODES - 8) mo = N_NODES - 8;
            gl_lds16(Vtb + (size_t)d * N_NODES + mo,
                     &Vts[buf][(w * 32 + p * 16) * 32]);
        }
    };

    // K fragments direct from global (row clamped into segment); 32 l-rows per wave
    bf16x8 afK[2][4];
    #pragma unroll
    for (int rg = 0; rg < 2; rg++) {
        int lrow = l0 + w * 32 + rg * 16 + i;
        if (lrow > c - 1) lrow = c - 1;
        const bf16* krow = Kb + (size_t)(seg + lrow) * DIM;
        #pragma unroll
        for (int ks = 0; ks < 4; ks++)
            afK[rg][ks] = *(const bf16x8*)(krow + ks * 32 + q * 8);
    }

    stage(0, mstart);                        // depth-2 pipeline prologue
    if (nch > 1) stage(1, mstart + 32);

    float li[2][4] = {{0,0,0,0},{0,0,0,0}};
    f32x4 Oc[2][8];
    #pragma unroll
    for (int rg = 0; rg < 2; rg++)
        #pragma unroll
        for (int t = 0; t < 8; t++) Oc[rg][t] = (f32x4){0,0,0,0};

    const int f7 = i & 7;                    // Q-read swizzle term (= row&7)
    const int tvi = (i ^ (i >> 2)) & 3;      // Vt/P read swizzle term

    for (int mc = 0; mc < nch; mc++) {
        const int cur = mc % 3;
        const int mbase = mstart + (mc << 5);
        // counted wait: retire chunk mc's 4 DMAs; chunk mc+1's 4 stay in flight
        if (mc + 1 < nch) asm volatile("s_waitcnt vmcnt(4)" ::: "memory");
        else              asm volatile("s_waitcnt vmcnt(0)" ::: "memory");
        __builtin_amdgcn_s_barrier();
        __builtin_amdgcn_sched_barrier(0);
        // buf (mc+2)%3 was fully consumed in iteration mc-1 (readers passed this barrier)
        if (mc + 2 < nch) stage((mc + 2) % 3, mbase + 64);

        const bf16* QsB = Qs[cur];
        const bf16* VtB = Vts[cur];
        bf16* Pw = &Qs[cur][w * 1024];       // wave-private 32x32 P slice (overlay)

        // S = K * Q^T (32 l-rows x 32 m-cols per wave): 8 bq reads feed 16 MFMAs
        f32x4 s[2][2];
        __builtin_amdgcn_s_setprio(1);
        #pragma unroll
        for (int ti = 0; ti < 2; ti++) {
            f32x4 a0 = {0,0,0,0}, a1 = {0,0,0,0};
            #pragma unroll
            for (int ks = 0; ks < 4; ks++) {
                bf16x8 bq = *(const bf16x8*)&QsB[(ti * 16 + i) * 128 + (((ks * 4 + q) ^ f7) << 3)];
                a0 = __builtin_amdgcn_mfma_f32_16x16x32_bf16(afK[0][ks], bq, a0, 0, 0, 0);
                a1 = __builtin_amdgcn_mfma_f32_16x16x32_bf16(afK[1][ks], bq, a1, 0, 0, 0);
            }
            s[0][ti] = a0; s[1][ti] = a1;
        }
        __builtin_amdgcn_s_setprio(0);
        if (mc == 0 || mc == nch - 1) {      // only edge chunks can have invalid m
            #pragma unroll
            for (int ti = 0; ti < 2; ti++) {
                int mg = mbase + ti * 16 + i;
                bool valid = (mg >= seg) && (mg < seg + c);
                if (!valid) {
                    s[0][ti] = (f32x4){-1.0e30f, -1.0e30f, -1.0e30f, -1.0e30f};
                    s[1][ti] = s[0][ti];
                }
            }
        }
        // p = exp2(s) in registers; accumulate l per-lane
        #pragma unroll
        for (int rg = 0; rg < 2; rg++)
            #pragma unroll
            for (int ti = 0; ti < 2; ti++)
                #pragma unroll
                for (int r = 0; r < 4; r++) {
                    float pv = exp2f(s[rg][ti][r]);
                    li[rg][r] += pv;
                    s[rg][ti][r] = pv;
                }

        // raw barrier: all waves' Qs[cur] reads retired; DMA (vmcnt) stays in flight
        asm volatile("s_waitcnt lgkmcnt(0)" ::: "memory");
        __builtin_amdgcn_s_barrier();
        __builtin_amdgcn_sched_barrier(0);

        // write P into overlay (rows = wave's 32 l-rows, cols = 32 m), swizzled:
        // slot = colgranule ^ (q^r)   [q^r == (row ^ row>>2)&3 for row=rg*16+q*4+r]
        #pragma unroll
        for (int rg = 0; rg < 2; rg++)
            #pragma unroll
            for (int ti = 0; ti < 2; ti++)
                #pragma unroll
                for (int r = 0; r < 4; r++) {
                    int rowl = rg * 16 + q * 4 + r;
                    int slot = (ti * 2 + (i >> 3)) ^ (q ^ r);
                    Pw[rowl * 32 + slot * 8 + f7] = (bf16)s[rg][ti][r];
                }

        // read P as A-fragments (same-wave LDS FIFO: no barrier needed)
        bf16x8 afP[2];
        #pragma unroll
        for (int rg = 0; rg < 2; rg++)
            afP[rg] = *(const bf16x8*)&Pw[(rg * 16 + i) * 32 + ((q ^ tvi) << 3)];

        // O += P * Vt: 8 bv reads feed 16 MFMAs
        __builtin_amdgcn_s_setprio(1);
        #pragma unroll
        for (int dt = 0; dt < 8; dt++) {
            bf16x8 bv = *(const bf16x8*)&VtB[(dt * 16 + i) * 32 + ((q ^ tvi) << 3)];
            Oc[0][dt] = __builtin_amdgcn_mfma_f32_16x16x32_bf16(afP[0], bv, Oc[0][dt], 0, 0, 0);
            Oc[1][dt] = __builtin_amdgcn_mfma_f32_16x16x32_bf16(afP[1], bv, Oc[1][dt], 0, 0, 0);
        }
        __builtin_amdgcn_s_setprio(0);
    }

    // one-time l reduction across the 16 i-lanes
    #pragma unroll
    for (int st = 1; st < 16; st <<= 1)
        #pragma unroll
        for (int rg = 0; rg < 2; rg++)
            #pragma unroll
            for (int r = 0; r < 4; r++)
                li[rg][r] += __shfl_xor(li[rg][r], st);

    // epilogue: z = O/l, h = x + z, LayerNorm, store fp32
    float gv[8], bvv[8];
    #pragma unroll
    for (int t = 0; t < 8; t++) { gv[t] = gamma[t * 16 + i]; bvv[t] = beta[t * 16 + i]; }
    #pragma unroll
    for (int rg = 0; rg < 2; rg++)
        for (int r = 0; r < 4; r++) {
            int lg = l0 + w * 32 + rg * 16 + q * 4 + r;
            if (lg >= c) continue;           // uniform across the 16-lane shuffle group
            size_t node = (size_t)(seg + lg);
            float inv = 1.0f / li[rg][r];
            const float* xr = x + node * DIM;
            float h[8], sum = 0.0f, ss = 0.0f;
            #pragma unroll
            for (int t = 0; t < 8; t++) {
                float hv = xr[t * 16 + i] + Oc[rg][t][r] * inv;
                h[t] = hv;
                sum += hv; ss += hv * hv;
            }
            #pragma unroll
            for (int st = 1; st < 16; st <<= 1) {
                sum += __shfl_xor(sum, st);
                ss  += __shfl_xor(ss, st);
            }
            float mu = sum * (1.0f / 128.0f);
            float var = ss * (1.0f / 128.0f) - mu * mu;
            float rstd = rsqrtf(var + 1e-5f);
            float* op = out + node * DIM;
            #pragma unroll
            for (int t = 0; t < 8; t++)
                op[t * 16 + i] = (h[t] - mu) * rstd * gv[t] + bvv[t];
        }
}

extern "C" void kernel_launch(void* const* d_in, const int* in_sizes, int n_in,
                              void* d_out, int out_size, void* d_ws, size_t ws_size,
                              hipStream_t stream) {
    (void)in_sizes; (void)n_in; (void)out_size; (void)ws_size;
    const float* x     = (const float*)d_in[0];
    const float* Wk    = (const float*)d_in[1];
    const float* bk    = (const float*)d_in[2];
    const float* Wq    = (const float*)d_in[3];
    const float* bq    = (const float*)d_in[4];
    const float* Wv    = (const float*)d_in[5];
    const float* bv    = (const float*)d_in[6];
    const float* gamma = (const float*)d_in[7];
    const float* beta  = (const float*)d_in[8];
    const int*   batch = (const int*)d_in[9];
    float* out = (float*)d_out;

    char* ws = (char*)d_ws;
    int*  starts = (int*)(ws + WS_STARTS);
    bf16* Wf  = (bf16*)(ws + WS_WF);
    bf16* Kb  = (bf16*)(ws + WS_KB);
    bf16* Qb  = (bf16*)(ws + WS_QB);
    bf16* Vtb = (bf16*)(ws + WS_VTB);

    seg_starts_kernel<<<1, 512, 0, stream>>>(batch, starts);
    wconv_kernel<<<24, 256, 0, stream>>>(Wk, Wq, Wv, Wf);
    qkv_kernel<<<1024, 256, 0, stream>>>(x, Wf, bk, bq, bv, Kb, Qb, Vtb);
    attn_kernel<<<dim3(NG, 4), 256, 0, stream>>>(x, Kb, Qb, Vtb, gamma, beta, starts, out);
}